// Round 9
// baseline (496.079 us; speedup 1.0000x reference)
//
#include <hip/hip_runtime.h>
#include <hip/hip_bf16.h>

// GCN encoder: conv1(512->256) -> BN -> ReLU -> conv2(256->128) -> BN
// R15: R14 post-mortem showed merged k_build_gemm1 (70us) is gated by the
// BUILD part: 128 serial counting-sort blocks stretched ~3x by co-residency
// with gemm blocks (MfmaUtil 7% -> gemm needs only ~5us of MFMA). Fix:
// NDB 128->256 (NPB 196, CAP 10240) halves per-block serial work. Also
// k_finalize1 folded into gemm2 staging (sc/sh computed per-thread from
// stats/gamma/beta, 3KB L1-hot) -- kills a launch + sc1/sh1 round trip.
// 12 -> 11 dispatches. All other bodies byte-identical to R14.
// Kept: part||prep merge, build||gemm1 merge (blockIdx-range dispatch, 40KB
// LDS union), agg1 column-split, R7 streaming agg2, BM=64 GEMMs, BN1+ReLU
// fused in gemm2 staging, memset for gcursor+stats.

#define NN 50000
#define NE 1600000
#define DIN 512
#define D1 256
#define D2 128
#define EPSV 1e-5f
#define NBUCK 16    // src buckets (agg L2 lockstep); 4 bits in packed word
#define BSZ 3125    // nodes per src bucket (16*3125 = 50000)
#define NDB 256     // dst buckets (CSR build) -- R15: 2x parallelism
#define NPB 196     // nodes per dst bucket (256*196 = 50176 >= NN)
#define CAP 10240   // part capacity per dst bucket (mean 6272, +50 sigma)

typedef __attribute__((ext_vector_type(8))) short bf16x8_t;
typedef __attribute__((ext_vector_type(4))) float f32x4_t;

__device__ __forceinline__ float bf2f(unsigned short u) {
  return __uint_as_float(((unsigned int)u) << 16);
}
__device__ __forceinline__ unsigned short f2bf(float f) {
  unsigned int u = __float_as_uint(f);
  u += 0x7fffu + ((u >> 16) & 1u);   // RNE
  return (unsigned short)(u >> 16);
}
__device__ __forceinline__ unsigned int pk2(float a, float b) {
  __hip_bfloat162 h = __float22bfloat162_rn(make_float2(a, b));
  union { __hip_bfloat162 h; unsigned int u; } c;
  c.h = h;
  return c.u;
}

// ---------- L1: edge partition (blocks 0..255) + weight prep (256..895) ----------
// part: packed word = src (16b) | dst_local (9b, <<16) | src_bucket (4b, <<25)
__global__ __launch_bounds__(256) void k_part_prep(const int* __restrict__ src,
                                                   const int* __restrict__ dst,
                                                   int* __restrict__ gcursor,
                                                   unsigned int* __restrict__ part,
                                                   const float* __restrict__ W1,
                                                   const float* __restrict__ W2,
                                                   unsigned short* __restrict__ W1t,
                                                   unsigned short* __restrict__ W2t) {
  __shared__ int hist[NDB];
  __shared__ int curs[NDB];
  const int t = threadIdx.x;
  if (blockIdx.x < 256) {
    const int EB = NE / 256;  // 6250 edges per block
    const int e0 = blockIdx.x * EB;
    hist[t] = 0;
    __syncthreads();
    for (int i = t; i < EB; i += 256) {
      int d = dst[e0 + i];
      atomicAdd(&hist[d / NPB], 1);
    }
    __syncthreads();
    {
      int c = hist[t];
      curs[t] = (c > 0) ? atomicAdd(&gcursor[t], c) : 0;
    }
    __syncthreads();
    for (int i = t; i < EB; i += 256) {
      int s = src[e0 + i];
      int d = dst[e0 + i];
      int b = d / NPB;
      int dl = d - b * NPB;
      int sb = (unsigned)s / BSZ;
      unsigned int w = (unsigned)s | ((unsigned)dl << 16) | ((unsigned)sb << 25);
      int pos = atomicAdd(&curs[b], 1);
      if (pos < CAP) part[(size_t)b * CAP + pos] = w;
    }
  } else {
    int i = (blockIdx.x - 256) * 256 + t;
    if (i < DIN * D1) {  // W1t[n*DIN + k] = W1[k*D1 + n]
      int n = i / DIN, k = i - n * DIN;
      W1t[i] = f2bf(W1[(size_t)k * D1 + n]);
    } else {
      int j = i - DIN * D1;  // W2t[n*D1 + k] = W2[k*D2 + n]
      int n = j / D1, k = j - n * D1;
      W2t[j] = f2bf(W2[(size_t)k * D2 + n]);
    }
  }
}

// exclusive prefix over 256 bucket totals -> ebase
__global__ void k_bscan(const int* __restrict__ gcursor, int* __restrict__ ebase) {
  __shared__ int s[NDB];
  int t = threadIdx.x;  // blockDim = 256
  int v = gcursor[t];
  s[t] = v;
  __syncthreads();
  for (int off = 1; off < NDB; off <<= 1) {
    int a = (t >= off) ? s[t - off] : 0;
    __syncthreads();
    s[t] += a;
    __syncthreads();
  }
  ebase[t] = s[t] - v;
  if (t == NDB - 1) ebase[NDB] = s[t];
}

// ---------- L3: CSR counting sort (blocks 0..255) + GEMM1 (256..1037) ----------
// build: per dst-bucket LDS counting sort by (node_local, src_bucket); emits
// row_ptr, dis, col. gemm1: H1[M x 256] = x[M x 512] @ W1t^T, BM=64.
// LDS union: build cnt[3136]+tsum[256] (13.6KB); gemm1 As 8KB + Bs 32KB.
__global__ __launch_bounds__(256) void k_build_gemm1(const unsigned int* __restrict__ part,
                                                     const int* __restrict__ gcursor,
                                                     const int* __restrict__ ebase,
                                                     int* __restrict__ row_ptr,
                                                     float* __restrict__ dis,
                                                     int* __restrict__ col,
                                                     const float* __restrict__ A,
                                                     const unsigned short* __restrict__ Bt,
                                                     unsigned short* __restrict__ C, int M) {
  __shared__ __align__(16) char smem[40960];
  const int t = threadIdx.x;
  if (blockIdx.x < NDB) {
    // ---- CSR build ----
    const int NC = NPB * NBUCK;  // 3136 counters
    int* cnt = (int*)smem;                 // 12544 B
    int* tsum = (int*)(smem + 12544);      // 1024 B
    const int b = blockIdx.x;
    int m = gcursor[b];
    if (m > CAP) m = CAP;
    const int base = ebase[b];
    const unsigned int* my = part + (size_t)b * CAP;
    for (int i = t; i < NC; i += 256) cnt[i] = 0;
    __syncthreads();
    for (int i = t; i < m; i += 256) {
      unsigned int w = my[i];
      atomicAdd(&cnt[((w >> 16) & 0x1ff) * NBUCK + (w >> 25)], 1);
    }
    __syncthreads();
    // exclusive scan of cnt[0..NC)
    const int CHK = (NC + 255) / 256;  // 13
    int i0 = t * CHK;
    int sum = 0;
    for (int i = 0; i < CHK; i++) {
      int idx = i0 + i;
      if (idx < NC) sum += cnt[idx];
    }
    tsum[t] = sum;
    __syncthreads();
    for (int off = 1; off < 256; off <<= 1) {
      int a = (t >= off) ? tsum[t - off] : 0;
      __syncthreads();
      tsum[t] += a;
      __syncthreads();
    }
    int run = tsum[t] - sum;
    for (int i = 0; i < CHK; i++) {
      int idx = i0 + i;
      if (idx < NC) {
        int c = cnt[idx];
        cnt[idx] = run;
        run += c;
      }
    }
    __syncthreads();
    // row_ptr / dis from scan values
    const int n0 = b * NPB;
    for (int dl = t; dl < NPB; dl += 256) {
      int n = n0 + dl;
      if (n < NN) {
        int st = cnt[dl * NBUCK];
        int en = (dl * NBUCK + NBUCK < NC) ? cnt[dl * NBUCK + NBUCK] : m;
        row_ptr[n] = base + st;
        dis[n] = rsqrtf((float)(en - st + 1));  // +1 self loop
      }
    }
    if (b == NDB - 1 && t == 0) row_ptr[NN] = base + m;
    __syncthreads();
    // scatter (cnt now serves as cursors); col segment [base, base+m) is dense
    for (int i = t; i < m; i += 256) {
      unsigned int w = my[i];
      int pos = atomicAdd(&cnt[((w >> 16) & 0x1ff) * NBUCK + (w >> 25)], 1);
      col[base + pos] = w & 0xffff;
    }
  } else {
    // ---- GEMM1, BM=64: 4 waves in 1x4 N-grid, 64Mx64N each ----
    unsigned short* As = (unsigned short*)smem;           // 64*64*2 = 8192 B
    unsigned short* Bs = (unsigned short*)(smem + 8192);  // 256*64*2 = 32768 B
    const int wave = t >> 6, lane = t & 63;
    const int m0 = (blockIdx.x - NDB) * 64;
    const int wn = wave * 64;
    const int l8 = lane >> 3;
    const int lbs = (lane & 7) ^ l8;
    const int row_c = lane & 15, quad = lane >> 4;

    f32x4_t acc[4][4];
#pragma unroll
    for (int i = 0; i < 4; i++)
#pragma unroll
      for (int j = 0; j < 4; j++) acc[i][j] = (f32x4_t){0.f, 0.f, 0.f, 0.f};

    for (int k0 = 0; k0 < DIN; k0 += 64) {
#pragma unroll
      for (int j = 0; j < 8; j++) {
        int chunk = wave * 8 + j;  // 32 chunks x 8 rows = 256 B-rows
        int row = chunk * 8 + l8;
        const unsigned short* g = Bt + (size_t)row * DIN + k0 + lbs * 8;
        __builtin_amdgcn_global_load_lds(
            (const __attribute__((address_space(1))) unsigned int*)g,
            (__attribute__((address_space(3))) unsigned int*)(Bs + chunk * 512), 16, 0, 0);
      }
#pragma unroll
      for (int i = 0; i < 2; i++) {
        int bid = i * 256 + t;  // 64 rows x 8 slots = 512 slots
        int row = bid >> 3, pb = bid & 7;
        int lb = pb ^ (row & 7);
        int gm = m0 + row;
        if (gm >= M) gm = M - 1;
        const float4* s = (const float4*)(A + (size_t)gm * DIN + k0 + lb * 8);
        float4 v0 = s[0], v1 = s[1];
        uint4 o;
        o.x = pk2(v0.x, v0.y);
        o.y = pk2(v0.z, v0.w);
        o.z = pk2(v1.x, v1.y);
        o.w = pk2(v1.z, v1.w);
        *(uint4*)(As + row * 64 + pb * 8) = o;
      }
      __syncthreads();
#pragma unroll
      for (int ki = 0; ki < 2; ki++) {
        bf16x8_t af[4], bfr[4];
        int kb = ki * 4 + quad;
#pragma unroll
        for (int i = 0; i < 4; i++) {
          int ar = i * 16 + row_c;
          af[i] = *(const bf16x8_t*)(As + ar * 64 + ((kb ^ (ar & 7)) * 8));
          int br = wn + i * 16 + row_c;
          bfr[i] = *(const bf16x8_t*)(Bs + br * 64 + ((kb ^ (br & 7)) * 8));
        }
#pragma unroll
        for (int i = 0; i < 4; i++)
#pragma unroll
          for (int j = 0; j < 4; j++)
            acc[i][j] = __builtin_amdgcn_mfma_f32_16x16x32_bf16(af[i], bfr[j], acc[i][j], 0, 0, 0);
      }
      __syncthreads();
    }
#pragma unroll
    for (int i = 0; i < 4; i++) {
#pragma unroll
      for (int j = 0; j < 4; j++) {
        int colv = wn + j * 16 + row_c;
#pragma unroll
        for (int r = 0; r < 4; r++) {
          int gm = m0 + i * 16 + quad * 4 + r;
          if (gm < M) C[(size_t)gm * D1 + colv] = f2bf(acc[i][j][r]);
        }
      }
    }
  }
}

// ---------- GEMM2: H2[M x 128] = relu(BN(A1))[M x 256] @ W2t[128 x 256]^T ----------
// BM=64 (782 blocks), 128 threads = 2 waves. R15: BN1 scale/shift computed
// inline from stats/gamma/beta (3KB L1-hot) -- finalize1 kernel removed.
__global__ __launch_bounds__(128) void k_gemm2(const unsigned short* __restrict__ A,
                                               const float* __restrict__ stats,
                                               const float* __restrict__ gamma,
                                               const float* __restrict__ beta,
                                               const unsigned short* __restrict__ Bt,
                                               unsigned short* __restrict__ C, int M) {
  __shared__ unsigned short As[64 * 64];
  __shared__ unsigned short Bs[128 * 64];
  const int t = threadIdx.x;
  const int wave = t >> 6, lane = t & 63;
  const int m0 = blockIdx.x * 64;
  const int wn = wave * 64;
  const int l8 = lane >> 3;
  const int lbs = (lane & 7) ^ l8;
  const int row_c = lane & 15, quad = lane >> 4;

  f32x4_t acc[4][4];
#pragma unroll
  for (int i = 0; i < 4; i++)
#pragma unroll
    for (int j = 0; j < 4; j++) acc[i][j] = (f32x4_t){0.f, 0.f, 0.f, 0.f};

  for (int k0 = 0; k0 < D1; k0 += 64) {
#pragma unroll
    for (int j = 0; j < 8; j++) {
      int chunk = wave * 8 + j;  // 16 chunks x 8 rows = 128 B-rows
      int row = chunk * 8 + l8;
      const unsigned short* g = Bt + (size_t)row * D1 + k0 + lbs * 8;
      __builtin_amdgcn_global_load_lds(
          (const __attribute__((address_space(1))) unsigned int*)g,
          (__attribute__((address_space(3))) unsigned int*)(Bs + chunk * 512), 16, 0, 0);
    }
#pragma unroll
    for (int i = 0; i < 4; i++) {
      int bid = i * 128 + t;  // 64 rows x 8 slots = 512 slots
      int row = bid >> 3, pb = bid & 7;
      int lb = pb ^ (row & 7);
      int gm = m0 + row;
      if (gm >= M) gm = M - 1;
      int colb = k0 + lb * 8;
      uint4 raw = *(const uint4*)(A + (size_t)gm * D1 + colb);
      float4 s0 = *(const float4*)(stats + colb);
      float4 s1 = *(const float4*)(stats + colb + 4);
      float4 q0 = *(const float4*)(stats + D1 + colb);
      float4 q1 = *(const float4*)(stats + D1 + colb + 4);
      float4 gA = *(const float4*)(gamma + colb);
      float4 gB = *(const float4*)(gamma + colb + 4);
      float4 bA = *(const float4*)(beta + colb);
      float4 bB = *(const float4*)(beta + colb + 4);
      const float inv = 1.0f / NN;
      float m0v = s0.x * inv, m1 = s0.y * inv, m2 = s0.z * inv, m3 = s0.w * inv;
      float m4 = s1.x * inv, m5 = s1.y * inv, m6 = s1.z * inv, m7 = s1.w * inv;
      float c0 = gA.x * rsqrtf(q0.x * inv - m0v * m0v + EPSV);
      float c1 = gA.y * rsqrtf(q0.y * inv - m1 * m1 + EPSV);
      float c2 = gA.z * rsqrtf(q0.z * inv - m2 * m2 + EPSV);
      float c3 = gA.w * rsqrtf(q0.w * inv - m3 * m3 + EPSV);
      float c4 = gB.x * rsqrtf(q1.x * inv - m4 * m4 + EPSV);
      float c5 = gB.y * rsqrtf(q1.y * inv - m5 * m5 + EPSV);
      float c6 = gB.z * rsqrtf(q1.z * inv - m6 * m6 + EPSV);
      float c7 = gB.w * rsqrtf(q1.w * inv - m7 * m7 + EPSV);
      float h0 = bA.x - m0v * c0, h1 = bA.y - m1 * c1;
      float h2 = bA.z - m2 * c2, h3 = bA.w - m3 * c3;
      float h4 = bB.x - m4 * c4, h5 = bB.y - m5 * c5;
      float h6 = bB.z - m6 * c6, h7 = bB.w - m7 * c7;
      float f0 = fmaxf(fmaf(bf2f((unsigned short)(raw.x & 0xffff)), c0, h0), 0.f);
      float f1 = fmaxf(fmaf(bf2f((unsigned short)(raw.x >> 16)),    c1, h1), 0.f);
      float f2 = fmaxf(fmaf(bf2f((unsigned short)(raw.y & 0xffff)), c2, h2), 0.f);
      float f3 = fmaxf(fmaf(bf2f((unsigned short)(raw.y >> 16)),    c3, h3), 0.f);
      float f4 = fmaxf(fmaf(bf2f((unsigned short)(raw.z & 0xffff)), c4, h4), 0.f);
      float f5 = fmaxf(fmaf(bf2f((unsigned short)(raw.z >> 16)),    c5, h5), 0.f);
      float f6 = fmaxf(fmaf(bf2f((unsigned short)(raw.w & 0xffff)), c6, h6), 0.f);
      float f7 = fmaxf(fmaf(bf2f((unsigned short)(raw.w >> 16)),    c7, h7), 0.f);
      uint4 o;
      o.x = pk2(f0, f1);
      o.y = pk2(f2, f3);
      o.z = pk2(f4, f5);
      o.w = pk2(f6, f7);
      *(uint4*)(As + row * 64 + pb * 8) = o;
    }
    __syncthreads();
#pragma unroll
    for (int ki = 0; ki < 2; ki++) {
      bf16x8_t af[4], bfr[4];
      int kb = ki * 4 + quad;
#pragma unroll
      for (int i = 0; i < 4; i++) {
        int ar = i * 16 + row_c;
        af[i] = *(const bf16x8_t*)(As + ar * 64 + ((kb ^ (ar & 7)) * 8));
        int br = wn + i * 16 + row_c;
        bfr[i] = *(const bf16x8_t*)(Bs + br * 64 + ((kb ^ (br & 7)) * 8));
      }
#pragma unroll
      for (int i = 0; i < 4; i++)
#pragma unroll
        for (int j = 0; j < 4; j++)
          acc[i][j] = __builtin_amdgcn_mfma_f32_16x16x32_bf16(af[i], bfr[j], acc[i][j], 0, 0, 0);
    }
    __syncthreads();
  }
#pragma unroll
  for (int i = 0; i < 4; i++) {
#pragma unroll
    for (int j = 0; j < 4; j++) {
      int colv = wn + j * 16 + row_c;  // < 128 = D2
#pragma unroll
      for (int r = 0; r < 4; r++) {
        int gm = m0 + i * 16 + quad * 4 + r;
        if (gm < M) C[(size_t)gm * D2 + colv] = f2bf(acc[i][j][r]);
      }
    }
  }
}

// ---------- CSR aggregation ----------
// agg1 split into two 128-column passes (half = 0/1): per-pass working set
// 12.8MB (3.2x per-XCD L2 oversubscription). Per 64-edge block: one coalesced
// col load + one dis gather, readlane broadcast to SGPRs, 8-deep row gathers.
__global__ __launch_bounds__(256) void k_agg1h(const unsigned short* __restrict__ H,
                                               const int* __restrict__ row_ptr,
                                               const int* __restrict__ col,
                                               const float* __restrict__ dis,
                                               const float* __restrict__ bias,
                                               unsigned short* __restrict__ OUT,
                                               int half) {
  int n = blockIdx.x * 4 + (threadIdx.x >> 6);
  int lane = threadIdx.x & 63;
  if (n >= NN) return;
  const unsigned short* Hh = H + half * 128;   // column-half base
  float dn = dis[n];
  ushort2 v = ((const ushort2*)(Hh + (size_t)n * D1))[lane];
  float wsf = dn * dn;
  float a0 = wsf * bf2f(v.x), a1 = wsf * bf2f(v.y);
  int e = row_ptr[n], e1 = row_ptr[n + 1];
  while (e < e1) {
    int cnt = e1 - e;
    if (cnt > 64) cnt = 64;
    int li = (lane < cnt) ? lane : (cnt - 1);
    int cv = col[e + li];                 // 64 edges' src ids, one load
    float dwv = dis[cv] * dn;             // 64 edges' weights, one gather
    int dwu = __float_as_int(dwv);
    int b = 0;
    for (; b + 8 <= cnt; b += 8) {
      int s[8];
      float w[8];
      ushort2 u[8];
#pragma unroll
      for (int k = 0; k < 8; k++) {
        s[k] = __builtin_amdgcn_readlane(cv, b + k);
        w[k] = __int_as_float(__builtin_amdgcn_readlane(dwu, b + k));
      }
#pragma unroll
      for (int k = 0; k < 8; k++)
        u[k] = ((const ushort2*)(Hh + (size_t)s[k] * D1))[lane];
#pragma unroll
      for (int k = 0; k < 8; k++) {
        a0 += w[k] * bf2f(u[k].x);
        a1 += w[k] * bf2f(u[k].y);
      }
    }
    for (; b < cnt; b++) {
      int sK = __builtin_amdgcn_readlane(cv, b);
      float wK = __int_as_float(__builtin_amdgcn_readlane(dwu, b));
      ushort2 uK = ((const ushort2*)(Hh + (size_t)sK * D1))[lane];
      a0 += wK * bf2f(uK.x);
      a1 += wK * bf2f(uK.y);
    }
    e += cnt;
  }
  int c = half * 128 + lane * 2;
  a0 += bias[c]; a1 += bias[c + 1];
  ushort2 o;
  o.x = f2bf(a0); o.y = f2bf(a1);
  ((ushort2*)(OUT + (size_t)n * D1 + half * 128))[lane] = o;
}

__global__ __launch_bounds__(256) void k_agg2(const unsigned short* __restrict__ H,
                                              const int* __restrict__ row_ptr,
                                              const int* __restrict__ col,
                                              const float* __restrict__ dis,
                                              const float* __restrict__ bias,
                                              float* __restrict__ OUT) {
  int n = blockIdx.x * 4 + (threadIdx.x >> 6);
  int lane = threadIdx.x & 63;
  if (n >= NN) return;
  float dn = dis[n];
  ushort2 v = ((const ushort2*)(H + (size_t)n * D2))[lane];
  float wsf = dn * dn;
  float a0 = wsf * bf2f(v.x), a1 = wsf * bf2f(v.y);
  int e = row_ptr[n], e1 = row_ptr[n + 1];
  while (e < e1) {
    int cnt = e1 - e;
    if (cnt > 64) cnt = 64;
    int li = (lane < cnt) ? lane : (cnt - 1);
    int cv = col[e + li];
    float dwv = dis[cv] * dn;
    int dwu = __float_as_int(dwv);
    int b = 0;
    for (; b + 8 <= cnt; b += 8) {
      int s[8];
      float w[8];
      ushort2 u[8];
#pragma unroll
      for (int k = 0; k < 8; k++) {
        s[k] = __builtin_amdgcn_readlane(cv, b + k);
        w[k] = __int_as_float(__builtin_amdgcn_readlane(dwu, b + k));
      }
#pragma unroll
      for (int k = 0; k < 8; k++)
        u[k] = ((const ushort2*)(H + (size_t)s[k] * D2))[lane];
#pragma unroll
      for (int k = 0; k < 8; k++) {
        a0 += w[k] * bf2f(u[k].x);
        a1 += w[k] * bf2f(u[k].y);
      }
    }
    for (; b < cnt; b++) {
      int sK = __builtin_amdgcn_readlane(cv, b);
      float wK = __int_as_float(__builtin_amdgcn_readlane(dwu, b));
      ushort2 uK = ((const ushort2*)(H + (size_t)sK * D2))[lane];
      a0 += wK * bf2f(uK.x);
      a1 += wK * bf2f(uK.y);
    }
    e += cnt;
  }
  int c = lane * 2;
  a0 += bias[c]; a1 += bias[c + 1];
  ((float2*)(OUT + (size_t)n * D2))[lane] = make_float2(a0, a1);
}

// ---------- BatchNorm stats ----------
__global__ void k_stats1(const unsigned short* __restrict__ X, float* __restrict__ stats) {
  int t = threadIdx.x;  // column 0..255
  int r0 = blockIdx.x * 64;
  int r1 = (r0 + 64 < NN) ? r0 + 64 : NN;
  float s = 0.f, q = 0.f;
  for (int r = r0; r < r1; r++) {
    float v = bf2f(X[(size_t)r * D1 + t]);
    s += v;
    q += v * v;
  }
  atomicAdd(&stats[t], s);
  atomicAdd(&stats[D1 + t], q);
}

__global__ void k_stats2(const float* __restrict__ X, float* __restrict__ stats) {
  int t = threadIdx.x;  // column 0..127
  int r0 = blockIdx.x * 128;
  int r1 = (r0 + 128 < NN) ? r0 + 128 : NN;
  float s = 0.f, q = 0.f;
  for (int r = r0; r < r1; r++) {
    float v = X[(size_t)r * D2 + t];
    s += v;
    q += v * v;
  }
  atomicAdd(&stats[t], s);
  atomicAdd(&stats[D2 + t], q);
}

__global__ void k_apply2(float* __restrict__ X, const float* __restrict__ stats,
                         const float* __restrict__ gamma, const float* __restrict__ beta) {
  int i = blockIdx.x * blockDim.x + threadIdx.x;
  int c = i & (D2 - 1);
  float mean = stats[c] * (1.0f / NN);
  float var = stats[D2 + c] * (1.0f / NN) - mean * mean;
  float sc = gamma[c] * rsqrtf(var + EPSV);
  X[i] = (X[i] - mean) * sc + beta[c];
}

extern "C" void kernel_launch(void* const* d_in, const int* in_sizes, int n_in,
                              void* d_out, int out_size, void* d_ws, size_t ws_size,
                              hipStream_t stream) {
  const float* x  = (const float*)d_in[0];
  const int* ei   = (const int*)d_in[1];  // [2, NE], int32
  const int* srcv = ei;
  const int* dstv = ei + NE;
  const float* W1  = (const float*)d_in[2];
  const float* b1  = (const float*)d_in[3];
  const float* g1  = (const float*)d_in[4];
  const float* be1 = (const float*)d_in[5];
  const float* W2  = (const float*)d_in[6];
  const float* b2  = (const float*)d_in[7];
  const float* g2  = (const float*)d_in[8];
  const float* be2 = (const float*)d_in[9];
  float* out = (float*)d_out;

  char* ws = (char*)d_ws;
  size_t off = 0;
  auto alloc = [&](size_t bytes) {
    size_t cur = off;
    off = (off + bytes + 255) & ~(size_t)255;
    return cur;
  };
  // gcursor + stats adjacent -> one memset (1024 + 3072 bytes)
  int* gcursor   = (int*)(ws + alloc(NDB * 4));                  // 1024 B
  float* stats   = (float*)(ws + alloc((D1 * 2 + D2 * 2) * 4));  // 3072 B
  int* row_ptr   = (int*)(ws + alloc((NN + 1) * 4));
  float* dis     = (float*)(ws + alloc(NN * 4));
  int* ebase     = (int*)(ws + alloc((NDB + 1) * 4));
  int* col       = (int*)(ws + alloc((size_t)NE * 4));
  unsigned int* part = (unsigned int*)(ws + alloc((size_t)NDB * CAP * 4));  // own region
  unsigned short* H1  = (unsigned short*)(ws + alloc((size_t)NN * D1 * 2));
  unsigned short* A1  = (unsigned short*)(ws + alloc((size_t)NN * D1 * 2));
  unsigned short* H2  = (unsigned short*)(ws + alloc((size_t)NN * D2 * 2));
  unsigned short* W1t = (unsigned short*)(ws + alloc((size_t)DIN * D1 * 2));
  unsigned short* W2t = (unsigned short*)(ws + alloc((size_t)D1 * D2 * 2));
  float* stats2 = stats + D1 * 2;

  // zero gcursor + stats (adjacent, 4096 B)
  hipMemsetAsync(gcursor, 0, NDB * 4 + (D1 * 2 + D2 * 2) * 4, stream);

  // L1: edge partition || weight prep
  k_part_prep<<<256 + 640, 256, 0, stream>>>(srcv, dstv, gcursor, part, W1, W2, W1t, W2t);
  k_bscan<<<1, NDB, 0, stream>>>(gcursor, ebase);

  const int mb = (NN + 63) / 64;  // 782

  // L3: CSR counting sort || GEMM1
  k_build_gemm1<<<NDB + mb, 256, 0, stream>>>(part, gcursor, ebase, row_ptr, dis, col,
                                              x, W1t, H1, NN);

  // conv1 aggregation (two column halves) + BN1 stats
  k_agg1h<<<(NN + 3) / 4, 256, 0, stream>>>(H1, row_ptr, col, dis, b1, A1, 0);
  k_agg1h<<<(NN + 3) / 4, 256, 0, stream>>>(H1, row_ptr, col, dis, b1, A1, 1);
  k_stats1<<<(NN + 63) / 64, 256, 0, stream>>>(A1, stats);

  // conv2 (BN1 scale/shift inline from stats)
  k_gemm2<<<mb, 128, 0, stream>>>(A1, stats, g1, be1, W2t, H2, NN);
  k_agg2<<<(NN + 3) / 4, 256, 0, stream>>>(H2, row_ptr, col, dis, b2, out);
  k_stats2<<<(NN + 127) / 128, 128, 0, stream>>>(out, stats2);
  k_apply2<<<NN * D2 / 256, 256, 0, stream>>>(out, stats2, g2, be2);
}

// Round 10
// 479.822 us; speedup vs baseline: 1.0339x; 1.0339x over previous
//
#include <hip/hip_runtime.h>
#include <hip/hip_bf16.h>

// GCN encoder: conv1(512->256) -> BN -> ReLU -> conv2(256->128) -> BN
// R16: (1) Revert R15's BN1-inline fold (cost ~+11us: 16x redundant rsqrtf in
// gemm2 staging) -- k_finalize1 restored, gemm2 body = R14 exact. Keep R15's
// NDB=256 build (70->61us, confirmed). (2) k_bscan folded into build blocks:
// each of the 256 build blocks scans gcursor[256] in LDS itself (1KB L2-hot,
// <1us, parallel) -- kills the serial 1-block launch. (3) Two agg1h launches
// merged into one 25000-block kernel (half = blockIdx>=12500; dispatch order
// preserves the half0-then-half1 phasing). 11 -> 10 dispatches.
// Kept: part||prep merge, build||gemm1 merge (40KB LDS union), agg1
// column-split, R7 streaming agg2, BM=64 GEMMs, memset for gcursor+stats.

#define NN 50000
#define NE 1600000
#define DIN 512
#define D1 256
#define D2 128
#define EPSV 1e-5f
#define NBUCK 16    // src buckets (agg L2 lockstep); 4 bits in packed word
#define BSZ 3125    // nodes per src bucket (16*3125 = 50000)
#define NDB 256     // dst buckets (CSR build)
#define NPB 196     // nodes per dst bucket (256*196 = 50176 >= NN)
#define CAP 10240   // part capacity per dst bucket (mean 6272, +50 sigma)
#define AGB ((NN + 3) / 4)   // 12500 agg blocks per column half

typedef __attribute__((ext_vector_type(8))) short bf16x8_t;
typedef __attribute__((ext_vector_type(4))) float f32x4_t;

__device__ __forceinline__ float bf2f(unsigned short u) {
  return __uint_as_float(((unsigned int)u) << 16);
}
__device__ __forceinline__ unsigned short f2bf(float f) {
  unsigned int u = __float_as_uint(f);
  u += 0x7fffu + ((u >> 16) & 1u);   // RNE
  return (unsigned short)(u >> 16);
}
__device__ __forceinline__ unsigned int pk2(float a, float b) {
  __hip_bfloat162 h = __float22bfloat162_rn(make_float2(a, b));
  union { __hip_bfloat162 h; unsigned int u; } c;
  c.h = h;
  return c.u;
}

// ---------- L1: edge partition (blocks 0..255) + weight prep (256..895) ----------
// part: packed word = src (16b) | dst_local (9b, <<16) | src_bucket (4b, <<25)
__global__ __launch_bounds__(256) void k_part_prep(const int* __restrict__ src,
                                                   const int* __restrict__ dst,
                                                   int* __restrict__ gcursor,
                                                   unsigned int* __restrict__ part,
                                                   const float* __restrict__ W1,
                                                   const float* __restrict__ W2,
                                                   unsigned short* __restrict__ W1t,
                                                   unsigned short* __restrict__ W2t) {
  __shared__ int hist[NDB];
  __shared__ int curs[NDB];
  const int t = threadIdx.x;
  if (blockIdx.x < 256) {
    const int EB = NE / 256;  // 6250 edges per block
    const int e0 = blockIdx.x * EB;
    hist[t] = 0;
    __syncthreads();
    for (int i = t; i < EB; i += 256) {
      int d = dst[e0 + i];
      atomicAdd(&hist[d / NPB], 1);
    }
    __syncthreads();
    {
      int c = hist[t];
      curs[t] = (c > 0) ? atomicAdd(&gcursor[t], c) : 0;
    }
    __syncthreads();
    for (int i = t; i < EB; i += 256) {
      int s = src[e0 + i];
      int d = dst[e0 + i];
      int b = d / NPB;
      int dl = d - b * NPB;
      int sb = (unsigned)s / BSZ;
      unsigned int w = (unsigned)s | ((unsigned)dl << 16) | ((unsigned)sb << 25);
      int pos = atomicAdd(&curs[b], 1);
      if (pos < CAP) part[(size_t)b * CAP + pos] = w;
    }
  } else {
    int i = (blockIdx.x - 256) * 256 + t;
    if (i < DIN * D1) {  // W1t[n*DIN + k] = W1[k*D1 + n]
      int n = i / DIN, k = i - n * DIN;
      W1t[i] = f2bf(W1[(size_t)k * D1 + n]);
    } else {
      int j = i - DIN * D1;  // W2t[n*D1 + k] = W2[k*D2 + n]
      int n = j / D1, k = j - n * D1;
      W2t[j] = f2bf(W2[(size_t)k * D2 + n]);
    }
  }
}

// ---------- L2: CSR counting sort (blocks 0..255) + GEMM1 (256..1037) ----------
// build: inline 256-wide prefix of gcursor (bscan folded in), then per
// dst-bucket LDS counting sort by (node_local, src_bucket); emits row_ptr,
// dis, col. gemm1: H1[M x 256] = x[M x 512] @ W1t^T, BM=64.
// LDS union: build gsc[256] -> cnt[3136]+tsum[256]; gemm1 As 8KB + Bs 32KB.
__global__ __launch_bounds__(256) void k_build_gemm1(const unsigned int* __restrict__ part,
                                                     const int* __restrict__ gcursor,
                                                     int* __restrict__ row_ptr,
                                                     float* __restrict__ dis,
                                                     int* __restrict__ col,
                                                     const float* __restrict__ A,
                                                     const unsigned short* __restrict__ Bt,
                                                     unsigned short* __restrict__ C, int M) {
  __shared__ __align__(16) char smem[40960];
  const int t = threadIdx.x;
  if (blockIdx.x < NDB) {
    // ---- inline bscan: base = exclusive prefix of gcursor[0..b) ----
    int* gsc = (int*)smem;
    const int b = blockIdx.x;
    int vb = gcursor[b];
    gsc[t] = gcursor[t];
    __syncthreads();
    for (int off = 1; off < NDB; off <<= 1) {
      int a = (t >= off) ? gsc[t - off] : 0;
      __syncthreads();
      gsc[t] += a;
      __syncthreads();
    }
    const int base = gsc[b] - vb;
    int m = vb;
    if (m > CAP) m = CAP;
    __syncthreads();   // done with gsc before cnt overwrites
    // ---- CSR build ----
    const int NC = NPB * NBUCK;  // 3136 counters
    int* cnt = (int*)smem;                 // 12544 B
    int* tsum = (int*)(smem + 12544);      // 1024 B
    const unsigned int* my = part + (size_t)b * CAP;
    for (int i = t; i < NC; i += 256) cnt[i] = 0;
    __syncthreads();
    for (int i = t; i < m; i += 256) {
      unsigned int w = my[i];
      atomicAdd(&cnt[((w >> 16) & 0x1ff) * NBUCK + (w >> 25)], 1);
    }
    __syncthreads();
    // exclusive scan of cnt[0..NC)
    const int CHK = (NC + 255) / 256;  // 13
    int i0 = t * CHK;
    int sum = 0;
    for (int i = 0; i < CHK; i++) {
      int idx = i0 + i;
      if (idx < NC) sum += cnt[idx];
    }
    tsum[t] = sum;
    __syncthreads();
    for (int off = 1; off < 256; off <<= 1) {
      int a = (t >= off) ? tsum[t - off] : 0;
      __syncthreads();
      tsum[t] += a;
      __syncthreads();
    }
    int run = tsum[t] - sum;
    for (int i = 0; i < CHK; i++) {
      int idx = i0 + i;
      if (idx < NC) {
        int c = cnt[idx];
        cnt[idx] = run;
        run += c;
      }
    }
    __syncthreads();
    // row_ptr / dis from scan values
    const int n0 = b * NPB;
    for (int dl = t; dl < NPB; dl += 256) {
      int n = n0 + dl;
      if (n < NN) {
        int st = cnt[dl * NBUCK];
        int en = (dl * NBUCK + NBUCK < NC) ? cnt[dl * NBUCK + NBUCK] : m;
        row_ptr[n] = base + st;
        dis[n] = rsqrtf((float)(en - st + 1));  // +1 self loop
      }
    }
    if (b == NDB - 1 && t == 0) row_ptr[NN] = base + m;
    __syncthreads();
    // scatter (cnt now serves as cursors); col segment [base, base+m) is dense
    for (int i = t; i < m; i += 256) {
      unsigned int w = my[i];
      int pos = atomicAdd(&cnt[((w >> 16) & 0x1ff) * NBUCK + (w >> 25)], 1);
      col[base + pos] = w & 0xffff;
    }
  } else {
    // ---- GEMM1, BM=64: 4 waves in 1x4 N-grid, 64Mx64N each ----
    unsigned short* As = (unsigned short*)smem;           // 64*64*2 = 8192 B
    unsigned short* Bs = (unsigned short*)(smem + 8192);  // 256*64*2 = 32768 B
    const int wave = t >> 6, lane = t & 63;
    const int m0 = (blockIdx.x - NDB) * 64;
    const int wn = wave * 64;
    const int l8 = lane >> 3;
    const int lbs = (lane & 7) ^ l8;
    const int row_c = lane & 15, quad = lane >> 4;

    f32x4_t acc[4][4];
#pragma unroll
    for (int i = 0; i < 4; i++)
#pragma unroll
      for (int j = 0; j < 4; j++) acc[i][j] = (f32x4_t){0.f, 0.f, 0.f, 0.f};

    for (int k0 = 0; k0 < DIN; k0 += 64) {
#pragma unroll
      for (int j = 0; j < 8; j++) {
        int chunk = wave * 8 + j;  // 32 chunks x 8 rows = 256 B-rows
        int row = chunk * 8 + l8;
        const unsigned short* g = Bt + (size_t)row * DIN + k0 + lbs * 8;
        __builtin_amdgcn_global_load_lds(
            (const __attribute__((address_space(1))) unsigned int*)g,
            (__attribute__((address_space(3))) unsigned int*)(Bs + chunk * 512), 16, 0, 0);
      }
#pragma unroll
      for (int i = 0; i < 2; i++) {
        int bid = i * 256 + t;  // 64 rows x 8 slots = 512 slots
        int row = bid >> 3, pb = bid & 7;
        int lb = pb ^ (row & 7);
        int gm = m0 + row;
        if (gm >= M) gm = M - 1;
        const float4* s = (const float4*)(A + (size_t)gm * DIN + k0 + lb * 8);
        float4 v0 = s[0], v1 = s[1];
        uint4 o;
        o.x = pk2(v0.x, v0.y);
        o.y = pk2(v0.z, v0.w);
        o.z = pk2(v1.x, v1.y);
        o.w = pk2(v1.z, v1.w);
        *(uint4*)(As + row * 64 + pb * 8) = o;
      }
      __syncthreads();
#pragma unroll
      for (int ki = 0; ki < 2; ki++) {
        bf16x8_t af[4], bfr[4];
        int kb = ki * 4 + quad;
#pragma unroll
        for (int i = 0; i < 4; i++) {
          int ar = i * 16 + row_c;
          af[i] = *(const bf16x8_t*)(As + ar * 64 + ((kb ^ (ar & 7)) * 8));
          int br = wn + i * 16 + row_c;
          bfr[i] = *(const bf16x8_t*)(Bs + br * 64 + ((kb ^ (br & 7)) * 8));
        }
#pragma unroll
        for (int i = 0; i < 4; i++)
#pragma unroll
          for (int j = 0; j < 4; j++)
            acc[i][j] = __builtin_amdgcn_mfma_f32_16x16x32_bf16(af[i], bfr[j], acc[i][j], 0, 0, 0);
      }
      __syncthreads();
    }
#pragma unroll
    for (int i = 0; i < 4; i++) {
#pragma unroll
      for (int j = 0; j < 4; j++) {
        int colv = wn + j * 16 + row_c;
#pragma unroll
        for (int r = 0; r < 4; r++) {
          int gm = m0 + i * 16 + quad * 4 + r;
          if (gm < M) C[(size_t)gm * D1 + colv] = f2bf(acc[i][j][r]);
        }
      }
    }
  }
}

// per-column BN1 scale/shift from stats
__global__ void k_finalize1(const float* __restrict__ stats, const float* __restrict__ gamma,
                            const float* __restrict__ beta, float* __restrict__ sc1,
                            float* __restrict__ sh1) {
  int c = threadIdx.x;  // 256
  float mean = stats[c] * (1.0f / NN);
  float var = stats[D1 + c] * (1.0f / NN) - mean * mean;
  float sc = gamma[c] * rsqrtf(var + EPSV);
  sc1[c] = sc;
  sh1[c] = beta[c] - mean * sc;
}

// ---------- GEMM2: H2[M x 128] = relu(BN(A1))[M x 256] @ W2t[128 x 256]^T ----------
// BM=64 (782 blocks), 128 threads = 2 waves in 1x2 N-grid, 64x64 each. (R14 body)
__global__ __launch_bounds__(128) void k_gemm2(const unsigned short* __restrict__ A,
                                               const float* __restrict__ sc1,
                                               const float* __restrict__ sh1,
                                               const unsigned short* __restrict__ Bt,
                                               unsigned short* __restrict__ C, int M) {
  __shared__ unsigned short As[64 * 64];
  __shared__ unsigned short Bs[128 * 64];
  const int t = threadIdx.x;
  const int wave = t >> 6, lane = t & 63;
  const int m0 = blockIdx.x * 64;
  const int wn = wave * 64;
  const int l8 = lane >> 3;
  const int lbs = (lane & 7) ^ l8;
  const int row_c = lane & 15, quad = lane >> 4;

  f32x4_t acc[4][4];
#pragma unroll
  for (int i = 0; i < 4; i++)
#pragma unroll
    for (int j = 0; j < 4; j++) acc[i][j] = (f32x4_t){0.f, 0.f, 0.f, 0.f};

  for (int k0 = 0; k0 < D1; k0 += 64) {
#pragma unroll
    for (int j = 0; j < 8; j++) {
      int chunk = wave * 8 + j;  // 16 chunks x 8 rows = 128 B-rows
      int row = chunk * 8 + l8;
      const unsigned short* g = Bt + (size_t)row * D1 + k0 + lbs * 8;
      __builtin_amdgcn_global_load_lds(
          (const __attribute__((address_space(1))) unsigned int*)g,
          (__attribute__((address_space(3))) unsigned int*)(Bs + chunk * 512), 16, 0, 0);
    }
#pragma unroll
    for (int i = 0; i < 4; i++) {
      int bid = i * 128 + t;  // 64 rows x 8 slots = 512 slots
      int row = bid >> 3, pb = bid & 7;
      int lb = pb ^ (row & 7);
      int gm = m0 + row;
      if (gm >= M) gm = M - 1;
      int colb = k0 + lb * 8;
      uint4 raw = *(const uint4*)(A + (size_t)gm * D1 + colb);
      float4 scA = *(const float4*)(sc1 + colb);
      float4 scB = *(const float4*)(sc1 + colb + 4);
      float4 shA = *(const float4*)(sh1 + colb);
      float4 shB = *(const float4*)(sh1 + colb + 4);
      float f0 = fmaxf(fmaf(bf2f((unsigned short)(raw.x & 0xffff)), scA.x, shA.x), 0.f);
      float f1 = fmaxf(fmaf(bf2f((unsigned short)(raw.x >> 16)),    scA.y, shA.y), 0.f);
      float f2 = fmaxf(fmaf(bf2f((unsigned short)(raw.y & 0xffff)), scA.z, shA.z), 0.f);
      float f3 = fmaxf(fmaf(bf2f((unsigned short)(raw.y >> 16)),    scA.w, shA.w), 0.f);
      float f4 = fmaxf(fmaf(bf2f((unsigned short)(raw.z & 0xffff)), scB.x, shB.x), 0.f);
      float f5 = fmaxf(fmaf(bf2f((unsigned short)(raw.z >> 16)),    scB.y, shB.y), 0.f);
      float f6 = fmaxf(fmaf(bf2f((unsigned short)(raw.w & 0xffff)), scB.z, shB.z), 0.f);
      float f7 = fmaxf(fmaf(bf2f((unsigned short)(raw.w >> 16)),    scB.w, shB.w), 0.f);
      uint4 o;
      o.x = pk2(f0, f1);
      o.y = pk2(f2, f3);
      o.z = pk2(f4, f5);
      o.w = pk2(f6, f7);
      *(uint4*)(As + row * 64 + pb * 8) = o;
    }
    __syncthreads();
#pragma unroll
    for (int ki = 0; ki < 2; ki++) {
      bf16x8_t af[4], bfr[4];
      int kb = ki * 4 + quad;
#pragma unroll
      for (int i = 0; i < 4; i++) {
        int ar = i * 16 + row_c;
        af[i] = *(const bf16x8_t*)(As + ar * 64 + ((kb ^ (ar & 7)) * 8));
        int br = wn + i * 16 + row_c;
        bfr[i] = *(const bf16x8_t*)(Bs + br * 64 + ((kb ^ (br & 7)) * 8));
      }
#pragma unroll
      for (int i = 0; i < 4; i++)
#pragma unroll
        for (int j = 0; j < 4; j++)
          acc[i][j] = __builtin_amdgcn_mfma_f32_16x16x32_bf16(af[i], bfr[j], acc[i][j], 0, 0, 0);
    }
    __syncthreads();
  }
#pragma unroll
  for (int i = 0; i < 4; i++) {
#pragma unroll
    for (int j = 0; j < 4; j++) {
      int colv = wn + j * 16 + row_c;  // < 128 = D2
#pragma unroll
      for (int r = 0; r < 4; r++) {
        int gm = m0 + i * 16 + quad * 4 + r;
        if (gm < M) C[(size_t)gm * D2 + colv] = f2bf(acc[i][j][r]);
      }
    }
  }
}

// ---------- CSR aggregation ----------
// agg1: both 128-column halves in ONE launch (blocks [0,AGB) = half 0,
// [AGB,2*AGB) = half 1; dispatch order preserves phasing). Per 64-edge block:
// one coalesced col load + one dis gather, readlane broadcast to SGPRs,
// 8-deep row gathers.
__global__ __launch_bounds__(256) void k_agg1(const unsigned short* __restrict__ H,
                                              const int* __restrict__ row_ptr,
                                              const int* __restrict__ col,
                                              const float* __restrict__ dis,
                                              const float* __restrict__ bias,
                                              unsigned short* __restrict__ OUT) {
  int bid = blockIdx.x;
  int half = (bid >= AGB) ? 1 : 0;
  int n = (bid - half * AGB) * 4 + (threadIdx.x >> 6);
  int lane = threadIdx.x & 63;
  if (n >= NN) return;
  const unsigned short* Hh = H + half * 128;   // column-half base
  float dn = dis[n];
  ushort2 v = ((const ushort2*)(Hh + (size_t)n * D1))[lane];
  float wsf = dn * dn;
  float a0 = wsf * bf2f(v.x), a1 = wsf * bf2f(v.y);
  int e = row_ptr[n], e1 = row_ptr[n + 1];
  while (e < e1) {
    int cnt = e1 - e;
    if (cnt > 64) cnt = 64;
    int li = (lane < cnt) ? lane : (cnt - 1);
    int cv = col[e + li];                 // 64 edges' src ids, one load
    float dwv = dis[cv] * dn;             // 64 edges' weights, one gather
    int dwu = __float_as_int(dwv);
    int b = 0;
    for (; b + 8 <= cnt; b += 8) {
      int s[8];
      float w[8];
      ushort2 u[8];
#pragma unroll
      for (int k = 0; k < 8; k++) {
        s[k] = __builtin_amdgcn_readlane(cv, b + k);
        w[k] = __int_as_float(__builtin_amdgcn_readlane(dwu, b + k));
      }
#pragma unroll
      for (int k = 0; k < 8; k++)
        u[k] = ((const ushort2*)(Hh + (size_t)s[k] * D1))[lane];
#pragma unroll
      for (int k = 0; k < 8; k++) {
        a0 += w[k] * bf2f(u[k].x);
        a1 += w[k] * bf2f(u[k].y);
      }
    }
    for (; b < cnt; b++) {
      int sK = __builtin_amdgcn_readlane(cv, b);
      float wK = __int_as_float(__builtin_amdgcn_readlane(dwu, b));
      ushort2 uK = ((const ushort2*)(Hh + (size_t)sK * D1))[lane];
      a0 += wK * bf2f(uK.x);
      a1 += wK * bf2f(uK.y);
    }
    e += cnt;
  }
  int c = half * 128 + lane * 2;
  a0 += bias[c]; a1 += bias[c + 1];
  ushort2 o;
  o.x = f2bf(a0); o.y = f2bf(a1);
  ((ushort2*)(OUT + (size_t)n * D1 + half * 128))[lane] = o;
}

__global__ __launch_bounds__(256) void k_agg2(const unsigned short* __restrict__ H,
                                              const int* __restrict__ row_ptr,
                                              const int* __restrict__ col,
                                              const float* __restrict__ dis,
                                              const float* __restrict__ bias,
                                              float* __restrict__ OUT) {
  int n = blockIdx.x * 4 + (threadIdx.x >> 6);
  int lane = threadIdx.x & 63;
  if (n >= NN) return;
  float dn = dis[n];
  ushort2 v = ((const ushort2*)(H + (size_t)n * D2))[lane];
  float wsf = dn * dn;
  float a0 = wsf * bf2f(v.x), a1 = wsf * bf2f(v.y);
  int e = row_ptr[n], e1 = row_ptr[n + 1];
  while (e < e1) {
    int cnt = e1 - e;
    if (cnt > 64) cnt = 64;
    int li = (lane < cnt) ? lane : (cnt - 1);
    int cv = col[e + li];
    float dwv = dis[cv] * dn;
    int dwu = __float_as_int(dwv);
    int b = 0;
    for (; b + 8 <= cnt; b += 8) {
      int s[8];
      float w[8];
      ushort2 u[8];
#pragma unroll
      for (int k = 0; k < 8; k++) {
        s[k] = __builtin_amdgcn_readlane(cv, b + k);
        w[k] = __int_as_float(__builtin_amdgcn_readlane(dwu, b + k));
      }
#pragma unroll
      for (int k = 0; k < 8; k++)
        u[k] = ((const ushort2*)(H + (size_t)s[k] * D2))[lane];
#pragma unroll
      for (int k = 0; k < 8; k++) {
        a0 += w[k] * bf2f(u[k].x);
        a1 += w[k] * bf2f(u[k].y);
      }
    }
    for (; b < cnt; b++) {
      int sK = __builtin_amdgcn_readlane(cv, b);
      float wK = __int_as_float(__builtin_amdgcn_readlane(dwu, b));
      ushort2 uK = ((const ushort2*)(H + (size_t)sK * D2))[lane];
      a0 += wK * bf2f(uK.x);
      a1 += wK * bf2f(uK.y);
    }
    e += cnt;
  }
  int c = lane * 2;
  a0 += bias[c]; a1 += bias[c + 1];
  ((float2*)(OUT + (size_t)n * D2))[lane] = make_float2(a0, a1);
}

// ---------- BatchNorm stats ----------
__global__ void k_stats1(const unsigned short* __restrict__ X, float* __restrict__ stats) {
  int t = threadIdx.x;  // column 0..255
  int r0 = blockIdx.x * 64;
  int r1 = (r0 + 64 < NN) ? r0 + 64 : NN;
  float s = 0.f, q = 0.f;
  for (int r = r0; r < r1; r++) {
    float v = bf2f(X[(size_t)r * D1 + t]);
    s += v;
    q += v * v;
  }
  atomicAdd(&stats[t], s);
  atomicAdd(&stats[D1 + t], q);
}

__global__ void k_stats2(const float* __restrict__ X, float* __restrict__ stats) {
  int t = threadIdx.x;  // column 0..127
  int r0 = blockIdx.x * 128;
  int r1 = (r0 + 128 < NN) ? r0 + 128 : NN;
  float s = 0.f, q = 0.f;
  for (int r = r0; r < r1; r++) {
    float v = X[(size_t)r * D2 + t];
    s += v;
    q += v * v;
  }
  atomicAdd(&stats[t], s);
  atomicAdd(&stats[D2 + t], q);
}

__global__ void k_apply2(float* __restrict__ X, const float* __restrict__ stats,
                         const float* __restrict__ gamma, const float* __restrict__ beta) {
  int i = blockIdx.x * blockDim.x + threadIdx.x;
  int c = i & (D2 - 1);
  float mean = stats[c] * (1.0f / NN);
  float var = stats[D2 + c] * (1.0f / NN) - mean * mean;
  float sc = gamma[c] * rsqrtf(var + EPSV);
  X[i] = (X[i] - mean) * sc + beta[c];
}

extern "C" void kernel_launch(void* const* d_in, const int* in_sizes, int n_in,
                              void* d_out, int out_size, void* d_ws, size_t ws_size,
                              hipStream_t stream) {
  const float* x  = (const float*)d_in[0];
  const int* ei   = (const int*)d_in[1];  // [2, NE], int32
  const int* srcv = ei;
  const int* dstv = ei + NE;
  const float* W1  = (const float*)d_in[2];
  const float* b1  = (const float*)d_in[3];
  const float* g1  = (const float*)d_in[4];
  const float* be1 = (const float*)d_in[5];
  const float* W2  = (const float*)d_in[6];
  const float* b2  = (const float*)d_in[7];
  const float* g2  = (const float*)d_in[8];
  const float* be2 = (const float*)d_in[9];
  float* out = (float*)d_out;

  char* ws = (char*)d_ws;
  size_t off = 0;
  auto alloc = [&](size_t bytes) {
    size_t cur = off;
    off = (off + bytes + 255) & ~(size_t)255;
    return cur;
  };
  // gcursor + stats adjacent -> one memset (1024 + 3072 bytes)
  int* gcursor   = (int*)(ws + alloc(NDB * 4));                  // 1024 B
  float* stats   = (float*)(ws + alloc((D1 * 2 + D2 * 2) * 4));  // 3072 B
  int* row_ptr   = (int*)(ws + alloc((NN + 1) * 4));
  float* dis     = (float*)(ws + alloc(NN * 4));
  float* sc1     = (float*)(ws + alloc(D1 * 4));
  float* sh1     = (float*)(ws + alloc(D1 * 4));
  int* col       = (int*)(ws + alloc((size_t)NE * 4));
  unsigned int* part = (unsigned int*)(ws + alloc((size_t)NDB * CAP * 4));  // own region
  unsigned short* H1  = (unsigned short*)(ws + alloc((size_t)NN * D1 * 2));
  unsigned short* A1  = (unsigned short*)(ws + alloc((size_t)NN * D1 * 2));
  unsigned short* H2  = (unsigned short*)(ws + alloc((size_t)NN * D2 * 2));
  unsigned short* W1t = (unsigned short*)(ws + alloc((size_t)DIN * D1 * 2));
  unsigned short* W2t = (unsigned short*)(ws + alloc((size_t)D1 * D2 * 2));
  float* stats2 = stats + D1 * 2;

  // zero gcursor + stats (adjacent, 4096 B)
  hipMemsetAsync(gcursor, 0, NDB * 4 + (D1 * 2 + D2 * 2) * 4, stream);

  // L1: edge partition || weight prep
  k_part_prep<<<256 + 640, 256, 0, stream>>>(srcv, dstv, gcursor, part, W1, W2, W1t, W2t);

  const int mb = (NN + 63) / 64;  // 782

  // L2: CSR counting sort (with inline bscan) || GEMM1
  k_build_gemm1<<<NDB + mb, 256, 0, stream>>>(part, gcursor, row_ptr, dis, col,
                                              x, W1t, H1, NN);

  // conv1 aggregation (both column halves, one launch) + BN1 stats
  k_agg1<<<2 * AGB, 256, 0, stream>>>(H1, row_ptr, col, dis, b1, A1);
  k_stats1<<<(NN + 63) / 64, 256, 0, stream>>>(A1, stats);
  k_finalize1<<<1, 256, 0, stream>>>(stats, g1, be1, sc1, sh1);

  // conv2
  k_gemm2<<<mb, 128, 0, stream>>>(A1, sc1, sh1, W2t, H2, NN);
  k_agg2<<<(NN + 3) / 4, 256, 0, stream>>>(H2, row_ptr, col, dis, b2, out);
  k_stats2<<<(NN + 127) / 128, 128, 0, stream>>>(out, stats2);
  k_apply2<<<NN * D2 / 256, 256, 0, stream>>>(out, stats2, g2, be2);
}